// Round 2
// baseline (219.648 us; speedup 1.0000x reference)
//
#include <hip/hip_runtime.h>
#include <math.h>

// Problem constants (fixed by the reference)
constexpr int B = 16384;
constexpr int D = 128;   // state dim
constexpr int H = 128;   // hidden
constexpr int O = 32;    // options
constexpr int A = 64;    // actions

constexpr int NB1 = 16;  // samples per block, phase 1
constexpr int NT1 = 256;
constexpr int TS  = 64;  // samples per tile, phase 2
constexpr int NT2 = 256;
constexpr int TILES_MAX = B / TS;   // 256 (worst case: all samples in one option)

// ws layout (as int*):
//   [0,32)        counts per option
//   [32,64)       cursors (scatter)
//   [64,96)       offsets (exclusive prefix)
//   [128,128+B)   sel per sample
//   [128+B, 128+2B) bucket (sample indices grouped by option)

__global__ void zero_ws(int* wsi) {
    if (threadIdx.x < 64) wsi[threadIdx.x] = 0;  // counts + cursors
}

__global__ __launch_bounds__(NT1) void phase1(
    const float* __restrict__ state, const float* __restrict__ u,
    const float* __restrict__ opt_w1, const float* __restrict__ opt_b1,
    const float* __restrict__ opt_w2, const float* __restrict__ opt_b2,
    const float* __restrict__ term_w1, const float* __restrict__ term_b1,
    const float* __restrict__ term_w2, const float* __restrict__ term_b2,
    float* __restrict__ out_optp, float* __restrict__ out_term,
    float* __restrict__ out_selopt,
    int* __restrict__ ws_sel, int* __restrict__ counts)
{
    __shared__ float s_x[NB1][D];      // 8KB; reused as hidden h after barrier
    __shared__ float s_probs[NB1][O];  // 2KB
    __shared__ float s_red[NB1][2];

    const int tid = threadIdx.x;
    const int b0  = blockIdx.x * NB1;

    // stage 16 state rows (512 float4 / 256 threads = 2 each)
    #pragma unroll
    for (int i = 0; i < 2; ++i) {
        const int lin = tid + i * NT1;
        const int row = lin >> 5, col = (lin & 31) << 2;
        *(float4*)&s_x[row][col] =
            *(const float4*)&state[(size_t)(b0 + row) * D + col];
    }
    __syncthreads();

    const int n    = tid & 127;
    const int half = tid >> 7;
    const int s0   = half * 8;

    // fused option-hidden + termination-hidden: 8 samples per thread
    float accO[8], accT[8];
    {
        const float bO = opt_b1[n], bT = term_b1[n];
        #pragma unroll
        for (int j = 0; j < 8; ++j) { accO[j] = bO; accT[j] = bT; }
        for (int d = 0; d < D; d += 4) {
            const float wO0 = opt_w1[(d + 0) * H + n];
            const float wO1 = opt_w1[(d + 1) * H + n];
            const float wO2 = opt_w1[(d + 2) * H + n];
            const float wO3 = opt_w1[(d + 3) * H + n];
            const float wT0 = term_w1[(d + 0) * H + n];
            const float wT1 = term_w1[(d + 1) * H + n];
            const float wT2 = term_w1[(d + 2) * H + n];
            const float wT3 = term_w1[(d + 3) * H + n];
            #pragma unroll
            for (int j = 0; j < 8; ++j) {
                const float4 x = *(const float4*)&s_x[s0 + j][d];
                accO[j] = fmaf(x.x, wO0, accO[j]);
                accO[j] = fmaf(x.y, wO1, accO[j]);
                accO[j] = fmaf(x.z, wO2, accO[j]);
                accO[j] = fmaf(x.w, wO3, accO[j]);
                accT[j] = fmaf(x.x, wT0, accT[j]);
                accT[j] = fmaf(x.y, wT1, accT[j]);
                accT[j] = fmaf(x.z, wT2, accT[j]);
                accT[j] = fmaf(x.w, wT3, accT[j]);
            }
        }
    }
    __syncthreads();            // all s_x reads done
    #pragma unroll
    for (int j = 0; j < 8; ++j)
        s_x[s0 + j][n] = fmaxf(accO[j], 0.f);   // reuse s_x as h

    // termination: partial = relu(accT)*w2[n], reduce over n
    {
        const float w2 = term_w2[n];
        const int lane = tid & 63, wv = tid >> 6;
        #pragma unroll
        for (int j = 0; j < 8; ++j) {
            float v = fmaxf(accT[j], 0.f) * w2;
            #pragma unroll
            for (int mask = 32; mask; mask >>= 1)
                v += __shfl_xor(v, mask, 64);
            if (lane == 0) s_red[s0 + j][wv & 1] = v;
        }
    }
    __syncthreads();

    // option logits + softmax: o = tid&31, 2 samples per thread
    {
        const int o  = tid & 31;
        const int sg = tid >> 5;
        const int t0 = sg * 2;
        float acc2[2];
        acc2[0] = opt_b2[o]; acc2[1] = opt_b2[o];
        for (int h = 0; h < H; h += 4) {
            const float w0 = opt_w2[(h + 0) * O + o];
            const float w1 = opt_w2[(h + 1) * O + o];
            const float w2 = opt_w2[(h + 2) * O + o];
            const float w3 = opt_w2[(h + 3) * O + o];
            #pragma unroll
            for (int j = 0; j < 2; ++j) {
                const float4 hv = *(const float4*)&s_x[t0 + j][h];
                acc2[j] = fmaf(hv.x, w0, acc2[j]);
                acc2[j] = fmaf(hv.y, w1, acc2[j]);
                acc2[j] = fmaf(hv.z, w2, acc2[j]);
                acc2[j] = fmaf(hv.w, w3, acc2[j]);
            }
        }
        #pragma unroll
        for (int j = 0; j < 2; ++j) {
            const float v = acc2[j];
            float m = v;
            #pragma unroll
            for (int mask = 16; mask; mask >>= 1)
                m = fmaxf(m, __shfl_xor(m, mask, 32));
            const float e = expf(v - m);
            float ss = e;
            #pragma unroll
            for (int mask = 16; mask; mask >>= 1)
                ss += __shfl_xor(ss, mask, 32);
            const float p = e / ss;
            s_probs[t0 + j][o] = p;
            out_optp[(size_t)(b0 + t0 + j) * O + o] = p;
        }
    }
    __syncthreads();

    // selection (exact sequential cumsum) + termination output
    if (tid < NB1) {
        const float uu = u[b0 + tid];
        float c = 0.f; int cnt = 0;
        for (int o = 0; o < O; ++o) {
            c += s_probs[tid][o];
            cnt += (c < uu) ? 1 : 0;
        }
        const int sel = (cnt < O - 1) ? cnt : (O - 1);
        out_selopt[b0 + tid] = (float)sel;
        ws_sel[b0 + tid] = sel;
        atomicAdd(&counts[sel], 1);
        const float x = s_red[tid][0] + s_red[tid][1] + term_b2[0];
        out_term[b0 + tid] = 1.f / (1.f + expf(-x));
    }
}

__global__ void prefix32(const int* __restrict__ counts, int* __restrict__ offsets) {
    if (threadIdx.x == 0) {
        int r = 0;
        for (int o = 0; o < O; ++o) { offsets[o] = r; r += counts[o]; }
    }
}

__global__ __launch_bounds__(256) void scatter(
    const int* __restrict__ ws_sel, const int* __restrict__ offsets,
    int* __restrict__ cursors, int* __restrict__ bucket)
{
    const int i = blockIdx.x * 256 + threadIdx.x;
    const int sel = ws_sel[i];
    const int pos = atomicAdd(&cursors[sel], 1);
    bucket[offsets[sel] + pos] = i;
}

__global__ __launch_bounds__(NT2) void phase2(
    const float* __restrict__ state,
    const float* __restrict__ exp_w1, const float* __restrict__ exp_b1,
    const float* __restrict__ exp_w2, const float* __restrict__ exp_b2,
    float* __restrict__ out_actp, float* __restrict__ out_selact,
    const int* __restrict__ counts, const int* __restrict__ offsets,
    const int* __restrict__ bucket)
{
    __shared__ float s_x[TS][D];   // 32KB; reused as hidden h
    __shared__ int   s_idx[TS];

    const int tile = blockIdx.x;
    const int o    = blockIdx.y;
    const int cnt  = counts[o];
    const int start = tile * TS;
    if (start >= cnt) return;
    const int nloc = min(TS, cnt - start);
    const int base = offsets[o] + start;
    const int tid  = threadIdx.x;

    if (tid < TS) s_idx[tid] = (tid < nloc) ? bucket[base + tid] : 0;
    __syncthreads();

    // gather 64 state rows (2048 float4 / 256 threads = 8 each)
    #pragma unroll
    for (int i = 0; i < 8; ++i) {
        const int lin = tid + i * NT2;
        const int row = lin >> 5, col = (lin & 31) << 2;
        float4 v = make_float4(0.f, 0.f, 0.f, 0.f);
        if (row < nloc)
            v = *(const float4*)&state[(size_t)s_idx[row] * D + col];
        *(float4*)&s_x[row][col] = v;
    }
    __syncthreads();

    // hidden: thread = 4 neurons (n4) x 8 samples
    const float* w1p = exp_w1 + (size_t)o * D * H;
    const int n4 = (tid & 31) << 2;
    const int sg = tid >> 5;      // 8 sample groups
    const int s0 = sg * 8;
    float4 acc[8];
    {
        const float4 bia = *(const float4*)&exp_b1[o * H + n4];
        #pragma unroll
        for (int j = 0; j < 8; ++j) acc[j] = bia;
    }
    for (int d = 0; d < D; d += 4) {
        const float4 w0 = *(const float4*)&w1p[(d + 0) * H + n4];
        const float4 w1 = *(const float4*)&w1p[(d + 1) * H + n4];
        const float4 w2 = *(const float4*)&w1p[(d + 2) * H + n4];
        const float4 w3 = *(const float4*)&w1p[(d + 3) * H + n4];
        #pragma unroll
        for (int j = 0; j < 8; ++j) {
            const float4 x = *(const float4*)&s_x[s0 + j][d];
            acc[j].x = fmaf(x.x, w0.x, acc[j].x);
            acc[j].y = fmaf(x.x, w0.y, acc[j].y);
            acc[j].z = fmaf(x.x, w0.z, acc[j].z);
            acc[j].w = fmaf(x.x, w0.w, acc[j].w);
            acc[j].x = fmaf(x.y, w1.x, acc[j].x);
            acc[j].y = fmaf(x.y, w1.y, acc[j].y);
            acc[j].z = fmaf(x.y, w1.z, acc[j].z);
            acc[j].w = fmaf(x.y, w1.w, acc[j].w);
            acc[j].x = fmaf(x.z, w2.x, acc[j].x);
            acc[j].y = fmaf(x.z, w2.y, acc[j].y);
            acc[j].z = fmaf(x.z, w2.z, acc[j].z);
            acc[j].w = fmaf(x.z, w2.w, acc[j].w);
            acc[j].x = fmaf(x.w, w3.x, acc[j].x);
            acc[j].y = fmaf(x.w, w3.y, acc[j].y);
            acc[j].z = fmaf(x.w, w3.z, acc[j].z);
            acc[j].w = fmaf(x.w, w3.w, acc[j].w);
        }
    }
    __syncthreads();            // all s_x reads done
    #pragma unroll
    for (int j = 0; j < 8; ++j) {
        float4 h;
        h.x = fmaxf(acc[j].x, 0.f); h.y = fmaxf(acc[j].y, 0.f);
        h.z = fmaxf(acc[j].z, 0.f); h.w = fmaxf(acc[j].w, 0.f);
        *(float4*)&s_x[s0 + j][n4] = h;   // reuse as h
    }
    __syncthreads();

    // logits: thread = 4 actions (a4) x 4 samples
    const float* w2p = exp_w2 + (size_t)o * H * A;
    const int a4 = (tid & 15) << 2;
    const int tg = tid >> 4;      // 16 sample groups
    const int t0 = tg * 4;
    float4 la[4];
    #pragma unroll
    for (int j = 0; j < 4; ++j) la[j] = make_float4(0.f, 0.f, 0.f, 0.f);
    for (int h = 0; h < H; h += 4) {
        const float4 w0 = *(const float4*)&w2p[(h + 0) * A + a4];
        const float4 w1 = *(const float4*)&w2p[(h + 1) * A + a4];
        const float4 w2 = *(const float4*)&w2p[(h + 2) * A + a4];
        const float4 w3 = *(const float4*)&w2p[(h + 3) * A + a4];
        #pragma unroll
        for (int j = 0; j < 4; ++j) {
            const float4 x = *(const float4*)&s_x[t0 + j][h];
            la[j].x = fmaf(x.x, w0.x, la[j].x);
            la[j].y = fmaf(x.x, w0.y, la[j].y);
            la[j].z = fmaf(x.x, w0.z, la[j].z);
            la[j].w = fmaf(x.x, w0.w, la[j].w);
            la[j].x = fmaf(x.y, w1.x, la[j].x);
            la[j].y = fmaf(x.y, w1.y, la[j].y);
            la[j].z = fmaf(x.y, w1.z, la[j].z);
            la[j].w = fmaf(x.y, w1.w, la[j].w);
            la[j].x = fmaf(x.z, w2.x, la[j].x);
            la[j].y = fmaf(x.z, w2.y, la[j].y);
            la[j].z = fmaf(x.z, w2.z, la[j].z);
            la[j].w = fmaf(x.z, w2.w, la[j].w);
            la[j].x = fmaf(x.w, w3.x, la[j].x);
            la[j].y = fmaf(x.w, w3.y, la[j].y);
            la[j].z = fmaf(x.w, w3.z, la[j].z);
            la[j].w = fmaf(x.w, w3.w, la[j].w);
        }
    }
    const float4 bias = *(const float4*)&exp_b2[o * A + a4];

    #pragma unroll
    for (int j = 0; j < 4; ++j) {
        const int s = t0 + j;
        float4 v;
        v.x = la[j].x + bias.x; v.y = la[j].y + bias.y;
        v.z = la[j].z + bias.z; v.w = la[j].w + bias.w;
        float m = fmaxf(fmaxf(v.x, v.y), fmaxf(v.z, v.w));
        #pragma unroll
        for (int mask = 8; mask; mask >>= 1)
            m = fmaxf(m, __shfl_xor(m, mask, 16));
        float4 e;
        e.x = expf(v.x - m); e.y = expf(v.y - m);
        e.z = expf(v.z - m); e.w = expf(v.w - m);
        float ss = e.x + e.y + e.z + e.w;
        #pragma unroll
        for (int mask = 8; mask; mask >>= 1)
            ss += __shfl_xor(ss, mask, 16);
        const float inv = 1.f / ss;
        float4 p;
        p.x = e.x * inv; p.y = e.y * inv; p.z = e.z * inv; p.w = e.w * inv;
        // argmax on probs, first-index tiebreak
        float bv = p.x; int bi = a4;
        if (p.y > bv) { bv = p.y; bi = a4 + 1; }
        if (p.z > bv) { bv = p.z; bi = a4 + 2; }
        if (p.w > bv) { bv = p.w; bi = a4 + 3; }
        #pragma unroll
        for (int mask = 8; mask; mask >>= 1) {
            const float ov = __shfl_xor(bv, mask, 16);
            const int   oi = __shfl_xor(bi, mask, 16);
            if (ov > bv || (ov == bv && oi < bi)) { bv = ov; bi = oi; }
        }
        if (s < nloc) {
            const int g = s_idx[s];
            *(float4*)&out_actp[(size_t)g * A + a4] = p;
            if ((tid & 15) == 0) out_selact[g] = (float)bi;
        }
    }
}

extern "C" void kernel_launch(void* const* d_in, const int* in_sizes, int n_in,
                              void* d_out, int out_size, void* d_ws, size_t ws_size,
                              hipStream_t stream) {
    const float* state   = (const float*)d_in[0];
    const float* u       = (const float*)d_in[1];
    const float* opt_w1  = (const float*)d_in[2];
    const float* opt_b1  = (const float*)d_in[3];
    const float* opt_w2  = (const float*)d_in[4];
    const float* opt_b2  = (const float*)d_in[5];
    const float* exp_w1  = (const float*)d_in[6];
    const float* exp_b1  = (const float*)d_in[7];
    const float* exp_w2  = (const float*)d_in[8];
    const float* exp_b2  = (const float*)d_in[9];
    const float* term_w1 = (const float*)d_in[10];
    const float* term_b1 = (const float*)d_in[11];
    const float* term_w2 = (const float*)d_in[12];
    const float* term_b2 = (const float*)d_in[13];

    float* out = (float*)d_out;
    float* out_optp   = out;                        // [B, O]
    float* out_actp   = out_optp + (size_t)B * O;   // [B, A]
    float* out_term   = out_actp + (size_t)B * A;   // [B, 1]
    float* out_selopt = out_term + B;               // [B]
    float* out_selact = out_selopt + B;             // [B]

    int* wsi = (int*)d_ws;
    int* counts  = wsi;
    int* cursors = wsi + 32;
    int* offsets = wsi + 64;
    int* ws_sel  = wsi + 128;
    int* bucket  = wsi + 128 + B;

    hipLaunchKernelGGL(zero_ws, dim3(1), dim3(64), 0, stream, wsi);
    hipLaunchKernelGGL(phase1, dim3(B / NB1), dim3(NT1), 0, stream,
                       state, u, opt_w1, opt_b1, opt_w2, opt_b2,
                       term_w1, term_b1, term_w2, term_b2,
                       out_optp, out_term, out_selopt, ws_sel, counts);
    hipLaunchKernelGGL(prefix32, dim3(1), dim3(32), 0, stream, counts, offsets);
    hipLaunchKernelGGL(scatter, dim3(B / 256), dim3(256), 0, stream,
                       ws_sel, offsets, cursors, bucket);
    hipLaunchKernelGGL(phase2, dim3(TILES_MAX, O), dim3(NT2), 0, stream,
                       state, exp_w1, exp_b1, exp_w2, exp_b2,
                       out_actp, out_selact, counts, offsets, bucket);
}